// Round 2
// baseline (967.868 us; speedup 1.0000x reference)
//
#include <hip/hip_runtime.h>
#include <math.h>

#define B 32
#define T 4096
#define D 1024
#define SCALE (1.0f / 32.0f)   // 1/sqrt(1024)

#define NCHUNK 32
#define TCHUNK (T / NCHUNK)    // 128

// ---------------- zero the out region (atomic accumulation target) ---------
__global__ __launch_bounds__(256) void zero_out_kernel(float* __restrict__ out) {
    int i = blockIdx.x * 256 + threadIdx.x;
    if (i < B * D) out[i] = 0.0f;
}

// ---------------- scores[b][t] = (q[b] . k[b][t]) * SCALE ------------------
// one wave (64 lanes) per t-row; 4 waves per block; q[b] staged in LDS
__global__ __launch_bounds__(256) void scores_kernel(const float* __restrict__ q,
                                                     const float* __restrict__ k,
                                                     float* __restrict__ attn) {
    int bid = blockIdx.x;              // 0 .. B*T/4 - 1
    int b   = bid / (T / 4);
    int t0  = (bid % (T / 4)) * 4;
    int tid = threadIdx.x;

    __shared__ float qs[D];
    ((float4*)qs)[tid] = ((const float4*)(q + (size_t)b * D))[tid]; // 256 * 16B = 4KB
    __syncthreads();

    int wave = tid >> 6;
    int lane = tid & 63;
    int t = t0 + wave;

    const float4* krow = (const float4*)(k + (size_t)b * T * D + (size_t)t * D);
    const float4* q4   = (const float4*)qs;

    float acc = 0.0f;
#pragma unroll
    for (int j = 0; j < 4; ++j) {
        float4 kv = krow[j * 64 + lane];
        float4 qv = q4[j * 64 + lane];
        acc += kv.x * qv.x + kv.y * qv.y + kv.z * qv.z + kv.w * qv.w;
    }
#pragma unroll
    for (int off = 32; off; off >>= 1) acc += __shfl_xor(acc, off, 64);

    if (lane == 0) attn[(size_t)b * T + t] = acc * SCALE;
}

// ---------------- softmax over T, in place ---------------------------------
// one block (1024 threads = 16 waves) per batch row; T/4 float4s = 1024
__global__ __launch_bounds__(1024) void softmax_kernel(float* __restrict__ attn) {
    int b = blockIdx.x;
    int tid = threadIdx.x;
    int wave = tid >> 6, lane = tid & 63;

    float4* row = (float4*)(attn + (size_t)b * T);
    float4 v = row[tid];

    __shared__ float redm[16];
    __shared__ float reds[16];

    // --- max ---
    float m = fmaxf(fmaxf(v.x, v.y), fmaxf(v.z, v.w));
#pragma unroll
    for (int off = 32; off; off >>= 1) m = fmaxf(m, __shfl_xor(m, off, 64));
    if (lane == 0) redm[wave] = m;
    __syncthreads();
    m = redm[0];
#pragma unroll
    for (int i = 1; i < 16; ++i) m = fmaxf(m, redm[i]);

    // --- exp + sum ---
    v.x = __expf(v.x - m);
    v.y = __expf(v.y - m);
    v.z = __expf(v.z - m);
    v.w = __expf(v.w - m);
    float s = v.x + v.y + v.z + v.w;
#pragma unroll
    for (int off = 32; off; off >>= 1) s += __shfl_xor(s, off, 64);
    if (lane == 0) reds[wave] = s;
    __syncthreads();
    s = 0.0f;
#pragma unroll
    for (int i = 0; i < 16; ++i) s += reds[i];

    float inv = 1.0f / s;
    v.x *= inv; v.y *= inv; v.z *= inv; v.w *= inv;
    row[tid] = v;
}

// ---------------- out[b][d] += sum_t attn[b][t] * v[b][t][d] ---------------
// block = (b, chunk of TCHUNK t-rows); thread owns one float4 of D
__global__ __launch_bounds__(256) void pv_kernel(const float* __restrict__ attn,
                                                 const float* __restrict__ val,
                                                 float* __restrict__ out) {
    int b = blockIdx.x / NCHUNK;
    int c = blockIdx.x % NCHUNK;
    int tid = threadIdx.x;

    __shared__ float a_lds[TCHUNK];
    if (tid < TCHUNK) a_lds[tid] = attn[(size_t)b * T + (size_t)c * TCHUNK + tid];
    __syncthreads();

    const float4* vbase = (const float4*)(val + (size_t)b * T * D + (size_t)c * TCHUNK * D);

    float4 acc = {0.0f, 0.0f, 0.0f, 0.0f};
#pragma unroll 4
    for (int i = 0; i < TCHUNK; ++i) {
        float a = a_lds[i];
        float4 vv = vbase[(size_t)i * (D / 4) + tid];
        acc.x += a * vv.x;
        acc.y += a * vv.y;
        acc.z += a * vv.z;
        acc.w += a * vv.w;
    }

    float* o = out + (size_t)b * D + (size_t)tid * 4;
    atomicAdd(o + 0, acc.x);
    atomicAdd(o + 1, acc.y);
    atomicAdd(o + 2, acc.z);
    atomicAdd(o + 3, acc.w);
}

extern "C" void kernel_launch(void* const* d_in, const int* in_sizes, int n_in,
                              void* d_out, int out_size, void* d_ws, size_t ws_size,
                              hipStream_t stream) {
    const float* q   = (const float*)d_in[0];   // [B, D]
    const float* k   = (const float*)d_in[1];   // [B, T, D]
    const float* val = (const float*)d_in[2];   // [B, T, D]

    float* out  = (float*)d_out;        // [B, D]
    float* attn = out + (size_t)B * D;  // [B, T]

    hipLaunchKernelGGL(zero_out_kernel, dim3((B * D) / 256), dim3(256), 0, stream, out);
    hipLaunchKernelGGL(scores_kernel,   dim3(B * T / 4),     dim3(256), 0, stream, q, k, attn);
    hipLaunchKernelGGL(softmax_kernel,  dim3(B),             dim3(1024), 0, stream, attn);
    hipLaunchKernelGGL(pv_kernel,       dim3(B * NCHUNK),    dim3(256), 0, stream, attn, val, out);
}